// Round 13
// baseline (4481.776 us; speedup 1.0000x reference)
//
#include <hip/hip_runtime.h>
#include <cstdint>
#include <cstddef>

#define NN 128
#define LL 512
#define DD 512
#define HH 1024
#define NJ 4096            // packed gate cols, j = 4*hc + g
#define ASTR 1024          // A row stride (fp16 elems)
#define BSTR 1024          // B row stride (fp16 elems)
#define NCH 4              // K chunks of 256 (each = 2 sub-chunks of 128)

// LDS offsets (shorts) within one 48KB buffer: A [2][32][128], B [2][64][128]
#define BUFS 24576

typedef __attribute__((ext_vector_type(8))) _Float16 half8;
typedef __attribute__((ext_vector_type(4))) float f32x4;

__device__ __forceinline__ unsigned short f2h(float x) {
  union { _Float16 h; unsigned short u; } v; v.h = (_Float16)x; return v.u;
}
__device__ __forceinline__ float sigf(float x) { return 1.0f / (1.0f + __expf(-x)); }

__device__ __forceinline__ void glds16(const void* g, const void* l) {
  __builtin_amdgcn_global_load_lds(
      (const __attribute__((address_space(1))) unsigned int*)g,
      (__attribute__((address_space(3))) unsigned int*)l, 16, 0, 0);
}

// ---------------- sT[l*NN + n] = sum_d X[n,l,d] ----------------
__global__ __launch_bounds__(256)
void sum_rows_kernel(const float* __restrict__ X, float* __restrict__ sT) {
  int row  = blockIdx.x * 4 + (threadIdx.x >> 6);
  int lane = threadIdx.x & 63;
  const float* x = X + (size_t)row * DD + lane * 8;
  float4 a = *(const float4*)x;
  float4 b = *(const float4*)(x + 4);
  float v = (a.x + a.y) + (a.z + a.w) + (b.x + b.y) + (b.z + b.w);
#pragma unroll
  for (int off = 32; off > 0; off >>= 1) v += __shfl_down(v, off, 64);
  if (lane == 0) {
    int n = row >> 9, l = row & 511;
    sT[l * NN + n] = v;
  }
}

// ---------------- pack W into fp16, gate-interleaved rows ----------------
__global__ __launch_bounds__(256)
void wpack_kernel(const float* __restrict__ Wi, const float* __restrict__ Wf,
                  const float* __restrict__ Wg, const float* __restrict__ Wo,
                  unsigned short* __restrict__ B) {
  int idx = blockIdx.x * 256 + threadIdx.x;    // NJ*128 threads
  int j = idx >> 7;
  int k = (idx & 127) << 3;
  int hc = j >> 2, g = j & 3;
  const float* W = (g == 0) ? Wi : (g == 1) ? Wf : (g == 2) ? Wg : Wo;
  const float4 x0 = *(const float4*)(W + (size_t)hc * HH + k);
  const float4 x1 = *(const float4*)(W + (size_t)hc * HH + k + 4);
  float xv[8] = {x0.x, x0.y, x0.z, x0.w, x1.x, x1.y, x1.z, x1.w};
  unsigned short* d = B + (size_t)j * BSTR + k;
#pragma unroll
  for (int e = 0; e < 8; ++e) d[e] = f2h(xv[e]);
}

// ---------------- pack lambda / (binv+b) gate-interleaved ----------------
__global__ __launch_bounds__(256)
void pack_kernel(const float* li, const float* lf, const float* lg, const float* lo_,
                 const float* bvi, const float* bvf, const float* bvg, const float* bvo,
                 const float* bi, const float* bf_, const float* bg, const float* bo,
                 float* __restrict__ lamP, float* __restrict__ biasP) {
  int j = blockIdx.x * 256 + threadIdx.x;
  int hc = j >> 2, g = j & 3;
  const float* lam = (g == 0) ? li : (g == 1) ? lf : (g == 2) ? lg : lo_;
  const float* bv  = (g == 0) ? bvi : (g == 1) ? bvf : (g == 2) ? bvg : bvo;
  const float* bb  = (g == 0) ? bi : (g == 1) ? bf_ : (g == 2) ? bg : bo;
  lamP[j] = lam[hc];
  biasP[j] = bv[hc] + bb[hc];
}

// ---------------- t = 0 (h=0, c=0: no GEMM) ----------------
__global__ __launch_bounds__(256)
void t0_kernel(const float* __restrict__ sT, const float* __restrict__ lamP,
               const float* __restrict__ biasP, float* __restrict__ out,
               float* __restrict__ cbuf, unsigned short* __restrict__ A0) {
  int id = blockIdx.x * 256 + threadIdx.x;   // NN*HH threads
  int n = id >> 10, hc = id & 1023;
  float sv = sT[n];                          // t = 0 slice
  float4 lam = *(const float4*)(lamP + 4 * hc);
  float4 bia = *(const float4*)(biasP + 4 * hc);
  float vi = sigf(sv * lam.x + bia.x);
  float vg = sigf(sv * lam.z + bia.z);
  float vo = sigf(sv * lam.w + bia.w);
  float cn = vi * vg;
  float hn = vo * sigf(cn);
  cbuf[n * HH + hc] = cn;
  out[(size_t)n * (LL * HH) + hc] = hn;
  A0[(size_t)n * ASTR + hc] = f2h(hn);
}

// ---------------- one LSTM step: fp16 GEMM, 2x2 register blocking ----------------
// grid 256 blocks (XCD-swizzled), block 128 thr = 2 waves (j-split 2x32).
// block tile 32m x 64j x K1024 (same as R11); wave tile 32m x 32j with 2x2
// blocking: 4 ds_read_b128 feed 4 MFMAs (1.0 reads/MFMA vs R11's 1.5).
// LDS layout, swizzle, glds16 staging, counted vmcnt: R11 verbatim
// (24 pieces/wave/chunk -> vmcnt(24)). Per-CU LDS reads 96->64 per chunk.
__global__ __launch_bounds__(128, 1)
void step_kernel(const unsigned short* __restrict__ Aprev,
                 const unsigned short* __restrict__ Bbuf,
                 const float* __restrict__ sT, const float* __restrict__ lamP,
                 const float* __restrict__ biasP, float* __restrict__ out,
                 float* __restrict__ cbuf, unsigned short* __restrict__ Acur, int t)
{
  __shared__ alignas(16) short lds[2][BUFS];   // 48 KB x 2

  const int tid = threadIdx.x;
  const int ln  = tid & 63;
  const int w   = tid >> 6;          // wave 0..1

  // XCD-contiguous mapping: XCD x owns Nt in [8x, 8x+8)
  const int bid = blockIdx.x;
  const int wl  = (bid & 7) * 32 + (bid >> 3);
  const int Nt  = wl >> 2;           // 0..63  (j tile)
  const int Mt  = wl & 3;            // 0..3   (m tile)
  const int n0  = Mt * 32;
  const int j0  = Nt * 64;

  // --- staging piece table: 48 pieces of 1KB/chunk; wave w owns 24 ---
  const char* srcb[24];
  int ldsoff[24];
  {
    const int ps = ln & 15;
    const int rr = ln >> 4;
#pragma unroll
    for (int i = 0; i < 24; ++i) {
      int sub = i >= 12;
      int pp = w * 12 + (i - sub * 12);       // 0..23
      const char* s; int off;
      if (pp < 8)  { int r = pp * 4 + rr;     int sp = (ps & 8) | ((ps ^ r) & 7);
                     s = (const char*)(Aprev + (size_t)(n0 + r) * ASTR + sub * 128 + sp * 8);
                     off = sub * 4096 + pp * 512; }
      else         { int pb = pp - 8;  int r = pb * 4 + rr;
                     int sp = (ps & 8) | ((ps ^ r) & 7);
                     s = (const char*)(Bbuf + (size_t)(j0 + r) * BSTR + sub * 128 + sp * 8);
                     off = 8192 + sub * 8192 + pb * 512; }
      srcb[i] = s; ldsoff[i] = off;
    }
  }

  // --- fragment read offsets (proven 128-col swizzle per sub-plane) ---
  int aoff[2][8], boff[2][8];
  {
    const int hs = ln >> 4;
#pragma unroll
    for (int sl = 0; sl < 8; ++sl) {
      int sub = sl >> 2;
      int s   = (sl & 3) * 4 + hs;
#pragma unroll
      for (int mf = 0; mf < 2; ++mf) {
        int rA = mf * 16 + (ln & 15);
        aoff[mf][sl] = sub * 4096 + rA * 128 + (((s & 8) | ((s ^ rA) & 7)) << 3);
      }
#pragma unroll
      for (int jf = 0; jf < 2; ++jf) {
        int rB = w * 32 + jf * 16 + (ln & 15);
        boff[jf][sl] = 8192 + sub * 8192 + rB * 128 + (((s & 8) | ((s ^ rB) & 7)) << 3);
      }
    }
  }

  // --- epilogue constants + prefetch (hide L2 latency under the K-loop) ---
  const int rbase = (ln >> 4) * 4;
  int jjv[2]; float lamv[2], biav[2];
#pragma unroll
  for (int jf = 0; jf < 2; ++jf) {
    jjv[jf] = j0 + w * 32 + jf * 16 + (ln & 15);
    lamv[jf] = lamP[jjv[jf]];
    biav[jf] = biasP[jjv[jf]];
  }
  float cold[2][2][4], svp[2][4];
#pragma unroll
  for (int mf = 0; mf < 2; ++mf)
#pragma unroll
    for (int r = 0; r < 4; ++r) {
      const int m = n0 + mf * 16 + rbase + r;
      svp[mf][r] = sT[t * NN + m];
#pragma unroll
      for (int jf = 0; jf < 2; ++jf)
        cold[jf][mf][r] = cbuf[m * HH + (jjv[jf] >> 2)];
    }

  f32x4 a00 = {0.f,0.f,0.f,0.f}, a01 = {0.f,0.f,0.f,0.f};
  f32x4 a10 = {0.f,0.f,0.f,0.f}, a11 = {0.f,0.f,0.f,0.f};

  auto stage = [&](int c, int b) {
    const int co = c * 512;            // K256 chunk = 512 B per row
#pragma unroll
    for (int i = 0; i < 24; ++i) glds16(srcb[i] + co, &lds[b][ldsoff[i]]);
  };

  stage(0, 0);
#pragma unroll
  for (int c = 0; c < NCH; ++c) {
    const int b = c & 1;
    __builtin_amdgcn_s_barrier();               // prev compute done: buf b^1 free
    if (c < NCH - 1) {
      stage(c + 1, b ^ 1);
      asm volatile("s_waitcnt vmcnt(24)" ::: "memory");  // chunk c landed; c+1 in flight
    } else {
      asm volatile("s_waitcnt vmcnt(0)" ::: "memory");
    }
    __builtin_amdgcn_s_barrier();               // all waves see chunk c
#pragma unroll
    for (int sl = 0; sl < 8; ++sl) {
      half8 fa0 = *(const half8*)&lds[b][aoff[0][sl]];
      half8 fa1 = *(const half8*)&lds[b][aoff[1][sl]];
      half8 fb0 = *(const half8*)&lds[b][boff[0][sl]];
      half8 fb1 = *(const half8*)&lds[b][boff[1][sl]];
      a00 = __builtin_amdgcn_mfma_f32_16x16x32_f16(fa0, fb0, a00, 0, 0, 0);
      a01 = __builtin_amdgcn_mfma_f32_16x16x32_f16(fa0, fb1, a01, 0, 0, 0);
      a10 = __builtin_amdgcn_mfma_f32_16x16x32_f16(fa1, fb0, a10, 0, 0, 0);
      a11 = __builtin_amdgcn_mfma_f32_16x16x32_f16(fa1, fb1, a11, 0, 0, 0);
    }
  }

  // ---- epilogue: fuse 4 gates (adjacent lanes) -> c,h ; emit h + h_fp16 ----
#pragma unroll
  for (int jf = 0; jf < 2; ++jf) {
    const int hc = jjv[jf] >> 2;
#pragma unroll
    for (int mf = 0; mf < 2; ++mf) {
      const int m0 = n0 + mf * 16 + rbase;
#pragma unroll
      for (int r = 0; r < 4; ++r) {
        const int m = m0 + r;
        float a = (jf == 0) ? ((mf == 0) ? a00[r] : a10[r])
                            : ((mf == 0) ? a01[r] : a11[r]);
        float v = sigf(a + svp[mf][r] * lamv[jf] + biav[jf]);
        const int base = ln & ~3;
        float vi = __shfl(v, base + 0, 64);
        float vf = __shfl(v, base + 1, 64);
        float vg = __shfl(v, base + 2, 64);
        float vo = __shfl(v, base + 3, 64);
        if ((ln & 3) == 0) {
          float cn = vf * cold[jf][mf][r] + vi * vg;
          float hn = vo * sigf(cn);
          cbuf[m * HH + hc] = cn;
          out[(size_t)m * (LL * HH) + (size_t)t * HH + hc] = hn;
          Acur[(size_t)m * ASTR + hc] = f2h(hn);
        }
      }
    }
  }
}

extern "C" void kernel_launch(void* const* d_in, const int* in_sizes, int n_in,
                              void* d_out, int out_size, void* d_ws, size_t ws_size,
                              hipStream_t stream) {
  const float* X    = (const float*)d_in[0];
  const float* lami = (const float*)d_in[1];
  const float* bvi  = (const float*)d_in[2];
  const float* Wi   = (const float*)d_in[3];
  const float* bi   = (const float*)d_in[4];
  const float* lamf = (const float*)d_in[5];
  const float* bvf  = (const float*)d_in[6];
  const float* Wf   = (const float*)d_in[7];
  const float* bf_  = (const float*)d_in[8];
  const float* lamg = (const float*)d_in[9];
  const float* bvg  = (const float*)d_in[10];
  const float* Wg   = (const float*)d_in[11];
  const float* bg   = (const float*)d_in[12];
  const float* lamo = (const float*)d_in[13];
  const float* bvo  = (const float*)d_in[14];
  const float* Wo   = (const float*)d_in[15];
  const float* bo   = (const float*)d_in[16];

  float* out  = (float*)d_out;

  // workspace layout (~9.7 MB)
  float* cbuf  = (float*)d_ws;                         // 128*1024 f32
  float* sT    = cbuf + (size_t)NN * HH;               // 512*128  f32
  float* lamP  = sT + (size_t)NN * LL;                 // 4096 f32
  float* biasP = lamP + NJ;                            // 4096 f32
  unsigned short* A0 = (unsigned short*)(biasP + NJ);  // 128*1024 fp16
  unsigned short* A1 = A0 + (size_t)NN * ASTR;         // 128*1024 fp16
  unsigned short* Bb = A1 + (size_t)NN * ASTR;         // 4096*1024 fp16 (8 MB)

  sum_rows_kernel<<<(NN * LL) / 4, 256, 0, stream>>>(X, sT);
  wpack_kernel<<<(NJ * 128) / 256, 256, 0, stream>>>(Wi, Wf, Wg, Wo, Bb);
  pack_kernel<<<NJ / 256, 256, 0, stream>>>(lami, lamf, lamg, lamo,
                                            bvi, bvf, bvg, bvo,
                                            bi, bf_, bg, bo, lamP, biasP);
  t0_kernel<<<(NN * HH) / 256, 256, 0, stream>>>(sT, lamP, biasP, out, cbuf, A0);

  for (int t = 1; t < LL; ++t) {
    const unsigned short* Ap = (t & 1) ? A0 : A1;
    unsigned short* Ac = (t & 1) ? (unsigned short*)A1 : A0;
    step_kernel<<<256, 128, 0, stream>>>(Ap, Bb, sT, lamP, biasP, out, cbuf, Ac, t);
  }
}

// Round 15
// 4254.323 us; speedup vs baseline: 1.0535x; 1.0535x over previous
//
#include <hip/hip_runtime.h>
#include <cstdint>
#include <cstddef>

#define NN 128
#define LL 512
#define DD 512
#define HH 1024
#define NJ 4096            // packed gate cols, j = 4*hc + g
#define ASTR 1024          // A row stride (fp16 elems)
#define BSTR 1024          // B row stride (fp16 elems)
#define NCH 4              // K chunks of 256

typedef __attribute__((ext_vector_type(8))) _Float16 half8;
typedef __attribute__((ext_vector_type(4))) float f32x4;
typedef __attribute__((ext_vector_type(4))) unsigned u32x4;

__device__ __forceinline__ unsigned short f2h(float x) {
  union { _Float16 h; unsigned short u; } v; v.h = (_Float16)x; return v.u;
}
__device__ __forceinline__ float sigf(float x) { return 1.0f / (1.0f + __expf(-x)); }

__device__ __forceinline__ void glds16(const void* g, const void* l) {
  __builtin_amdgcn_global_load_lds(
      (const __attribute__((address_space(1))) unsigned int*)g,
      (__attribute__((address_space(3))) unsigned int*)l, 16, 0, 0);
}

// coalesced coherent ops at the MALL coherence point (cross-XCD safe):
__device__ __forceinline__ u32x4 load16_sc(const void* p) {
  u32x4 r;
  asm volatile("global_load_dwordx4 %0, %1, off sc0 sc1" : "=v"(r) : "v"(p));
  return r;
}
__device__ __forceinline__ void store2_sc(void* p, unsigned v) {
  asm volatile("global_store_short %0, %1, off sc0 sc1" :: "v"(p), "v"(v) : "memory");
}
__device__ __forceinline__ void store4_sc(void* p, unsigned v) {
  asm volatile("global_store_dword %0, %1, off sc0 sc1" :: "v"(p), "v"(v) : "memory");
}
__device__ __forceinline__ unsigned load4_sc(const void* p) {
  unsigned r;
  asm volatile("global_load_dword %0, %1, off sc0 sc1\n\ts_waitcnt vmcnt(0)"
               : "=v"(r) : "v"(p) : "memory");
  return r;
}

// ---------------- zero flags THROUGH the coherence point ----------------
__global__ __launch_bounds__(256)
void zero_flags_kernel(unsigned* __restrict__ flags) {
  store4_sc(flags + threadIdx.x, 0u);
}

// ---------------- sT[l*NN + n] = sum_d X[n,l,d] ----------------
__global__ __launch_bounds__(256)
void sum_rows_kernel(const float* __restrict__ X, float* __restrict__ sT) {
  int row  = blockIdx.x * 4 + (threadIdx.x >> 6);
  int lane = threadIdx.x & 63;
  const float* x = X + (size_t)row * DD + lane * 8;
  float4 a = *(const float4*)x;
  float4 b = *(const float4*)(x + 4);
  float v = (a.x + a.y) + (a.z + a.w) + (b.x + b.y) + (b.z + b.w);
#pragma unroll
  for (int off = 32; off > 0; off >>= 1) v += __shfl_down(v, off, 64);
  if (lane == 0) {
    int n = row >> 9, l = row & 511;
    sT[l * NN + n] = v;
  }
}

// ---------------- pack W into fp16, gate-interleaved rows ----------------
__global__ __launch_bounds__(256)
void wpack_kernel(const float* __restrict__ Wi, const float* __restrict__ Wf,
                  const float* __restrict__ Wg, const float* __restrict__ Wo,
                  unsigned short* __restrict__ B) {
  int idx = blockIdx.x * 256 + threadIdx.x;    // NJ*128 threads
  int j = idx >> 7;
  int k = (idx & 127) << 3;
  int hc = j >> 2, g = j & 3;
  const float* W = (g == 0) ? Wi : (g == 1) ? Wf : (g == 2) ? Wg : Wo;
  const float4 x0 = *(const float4*)(W + (size_t)hc * HH + k);
  const float4 x1 = *(const float4*)(W + (size_t)hc * HH + k + 4);
  float xv[8] = {x0.x, x0.y, x0.z, x0.w, x1.x, x1.y, x1.z, x1.w};
  unsigned short* d = B + (size_t)j * BSTR + k;
#pragma unroll
  for (int e = 0; e < 8; ++e) d[e] = f2h(xv[e]);
}

// ---------------- pack lambda / (binv+b) gate-interleaved ----------------
__global__ __launch_bounds__(256)
void pack_kernel(const float* li, const float* lf, const float* lg, const float* lo_,
                 const float* bvi, const float* bvf, const float* bvg, const float* bvo,
                 const float* bi, const float* bf_, const float* bg, const float* bo,
                 float* __restrict__ lamP, float* __restrict__ biasP) {
  int j = blockIdx.x * 256 + threadIdx.x;
  int hc = j >> 2, g = j & 3;
  const float* lam = (g == 0) ? li : (g == 1) ? lf : (g == 2) ? lg : lo_;
  const float* bv  = (g == 0) ? bvi : (g == 1) ? bvf : (g == 2) ? bvg : bvo;
  const float* bb  = (g == 0) ? bi : (g == 1) ? bf_ : (g == 2) ? bg : bo;
  lamP[j] = lam[hc];
  biasP[j] = bv[hc] + bb[hc];
}

// ---------------- persistent LSTM: B resident in LDS, coalesced MALL A-exchange ----------------
// 256 blocks x 256 thr (4 waves), 144 KB LDS -> exactly 1 block/CU, all resident.
// B (64j x 1024K fp16 = 128 KB) staged ONCE via glds16, lives in LDS all 512 steps.
// A (h fp16, 256 KB/step) exchanged through the MALL coherence point with
// COALESCED sc0|sc1 vector ops (R8's atomics were per-lane transactions — the
// diagnosed 24.7 us/step cost). Flag-array sync (contention-free, R8-proven).
// Per step: 16 A-loads issued up-front; counted vmcnt(12/8/4/0); reg->swizzled
// ds_write (R7-proven mapping); compute = R11's exact fragment math.
__global__ __launch_bounds__(256, 1)
void persist_kernel(const unsigned short* __restrict__ Bbuf,
                    const float* __restrict__ sT,
                    const float* __restrict__ lamP,
                    const float* __restrict__ biasP,
                    float* __restrict__ out,
                    unsigned short* __restrict__ Ag0,
                    unsigned short* __restrict__ Ag1,
                    unsigned* __restrict__ flags)
{
  __shared__ alignas(16) short Bsm[65536];   // 128 KB: 8 planes [64][128], swizzled
  __shared__ alignas(16) short Asm[8192];    // 16 KB: 2 subs [32][128], swizzled

  const int tid = threadIdx.x;
  const int ln  = tid & 63;
  const int w   = tid >> 6;          // wave 0..3

  const int bid = blockIdx.x;
  const int wl  = (bid & 7) * 32 + (bid >> 3);   // XCD-contiguous (R11-proven)
  const int Nt  = wl >> 2;           // 0..63
  const int Mt  = wl & 3;            // 0..3
  const int n0  = Mt * 32;
  const int j0  = Nt * 64;
  unsigned* gf = flags + Mt * 64;

  const int ps = ln & 15;
  const int rr = ln >> 4;

  // ---- one-time B residency: 128 pieces of 1KB, 32 per wave ----
#pragma unroll
  for (int i = 0; i < 32; ++i) {
    int pb = w * 32 + i;             // 0..127
    int plane = pb >> 4, rg = pb & 15;
    int r  = rg * 4 + rr;            // 0..63
    int sp = (ps & 8) | ((ps ^ r) & 7);
    glds16(Bbuf + (size_t)(j0 + r) * BSTR + plane * 128 + sp * 8,
           &Bsm[plane * 8192 + rg * 512]);
  }
  asm volatile("s_waitcnt vmcnt(0)" ::: "memory");
  __builtin_amdgcn_s_barrier();

  // ---- A consumer mapping: thread -> row ar, 4 slots; swizzled ds_write dest ----
  const int ar = tid >> 3;           // 0..31
  int sQ[4], dQ[4];
#pragma unroll
  for (int q = 0; q < 4; ++q) {
    int s = (tid & 7) * 4 + q;       // 0..31
    int sub = s >> 4, sl16 = s & 15;
    sQ[q] = (sub * 128 + sl16 * 8) * 2;   // byte offset within row chunk-slice
    dQ[q] = sub * 4096 + ar * 128 + (((sl16 & 8) | ((sl16 ^ ar) & 7)) << 3);
  }
  const size_t arowb = (size_t)(n0 + ar) * (ASTR * 2);   // row base, bytes

  // ---- fragment read offsets (R11 swizzle, verbatim) ----
  int aoff[2][8], boff[8];
  {
    const int hs = ln >> 4;
#pragma unroll
    for (int sl = 0; sl < 8; ++sl) {
      int s = (sl & 3) * 4 + hs;
#pragma unroll
      for (int mf = 0; mf < 2; ++mf) {
        int rA = mf * 16 + (ln & 15);
        aoff[mf][sl] = (sl >> 2) * 4096 + rA * 128 + (((s & 8) | ((s ^ rA) & 7)) << 3);
      }
      int rB = w * 16 + (ln & 15);
      boff[sl] = (sl >> 2) * 8192 + rB * 128 + (((s & 8) | ((s ^ rB) & 7)) << 3);
    }
  }

  // ---- epilogue constants ----
  const int jj = j0 + w * 16 + (ln & 15);
  const float lamv = lamP[jj];
  const float biav = biasP[jj];
  const int rbase = rr * 4;
  const int hc = jj >> 2;
  float creg[2][4] = {{0.f,0.f,0.f,0.f},{0.f,0.f,0.f,0.f}};

  for (int t = 0; t < LL; ++t) {
    unsigned short* Acur = (t & 1) ? Ag1 : Ag0;
    f32x4 acc0 = {0.f,0.f,0.f,0.f};
    f32x4 acc1 = {0.f,0.f,0.f,0.f};

    // sT prefetch (flag-independent; oldest in vmcnt FIFO)
    float svp[2][4];
#pragma unroll
    for (int mf = 0; mf < 2; ++mf)
#pragma unroll
      for (int r = 0; r < 4; ++r)
        svp[mf][r] = sT[t * NN + n0 + mf * 16 + rbase + r];

    if (t > 0) {
      const unsigned short* Ap = (t & 1) ? Ag0 : Ag1;   // h(t-1)

      // wait for all 64 producer blocks of this Mt group
      if (w == 0) {
        const unsigned* fp = gf + ln;
        for (;;) {
          unsigned v = load4_sc(fp);
          if (__all((int)v >= t)) break;
          __builtin_amdgcn_s_sleep(2);
        }
      }
      __builtin_amdgcn_s_barrier();
      __builtin_amdgcn_sched_barrier(0);

      // issue ALL 16 A-loads (coalesced, sc0|sc1 -> MALL, bypasses stale L2)
      u32x4 rA[4][4];
      const char* abase = (const char*)Ap + arowb;
#pragma unroll
      for (int c2 = 0; c2 < 4; ++c2)
#pragma unroll
        for (int q = 0; q < 4; ++q)
          rA[c2][q] = load16_sc(abase + c2 * 512 + sQ[q]);
      __builtin_amdgcn_sched_barrier(0);

#pragma unroll
      for (int c = 0; c < NCH; ++c) {
        // counted wait: svp(8) + A-chunks<=c retired
        if (c == 0)      asm volatile("s_waitcnt vmcnt(12)" ::: "memory");
        else if (c == 1) asm volatile("s_waitcnt vmcnt(8)"  ::: "memory");
        else if (c == 2) asm volatile("s_waitcnt vmcnt(4)"  ::: "memory");
        else             asm volatile("s_waitcnt vmcnt(0)"  ::: "memory");
        __builtin_amdgcn_sched_barrier(0);
        // write chunk c into Asm (swizzled dest; Asm free: post-compute barrier)
#pragma unroll
        for (int q = 0; q < 4; ++q) *(u32x4*)&Asm[dQ[q]] = rA[c][q];
        asm volatile("s_waitcnt lgkmcnt(0)" ::: "memory");
        __builtin_amdgcn_s_barrier();
        // compute chunk c against resident B
#pragma unroll
        for (int sl = 0; sl < 8; ++sl) {
          half8 a0 = *(const half8*)&Asm[aoff[0][sl]];
          half8 a1 = *(const half8*)&Asm[aoff[1][sl]];
          half8 bb = *(const half8*)&Bsm[c * 16384 + boff[sl]];
          acc0 = __builtin_amdgcn_mfma_f32_16x16x32_f16(a0, bb, acc0, 0, 0, 0);
          acc1 = __builtin_amdgcn_mfma_f32_16x16x32_f16(a1, bb, acc1, 0, 0, 0);
        }
        __builtin_amdgcn_s_barrier();            // all waves done reading Asm
      }
    }

    // ---- epilogue: fuse 4 gates (adjacent lanes) -> c,h ; h to out + Acur(MALL) ----
#pragma unroll
    for (int mf = 0; mf < 2; ++mf) {
      const int m0 = n0 + mf * 16 + rbase;
#pragma unroll
      for (int r = 0; r < 4; ++r) {
        const int m = m0 + r;
        float a = (mf == 0) ? acc0[r] : acc1[r];
        float v = sigf(a + svp[mf][r] * lamv + biav);
        const int base = ln & ~3;
        float vi = __shfl(v, base + 0, 64);
        float vf = __shfl(v, base + 1, 64);
        float vg = __shfl(v, base + 2, 64);
        float vo = __shfl(v, base + 3, 64);
        float cn = vf * creg[mf][r] + vi * vg;   // garbage on non-leader lanes, unused
        creg[mf][r] = cn;
        float hn = vo * sigf(cn);
        if ((ln & 3) == 0) {
          out[(size_t)m * (LL * HH) + (size_t)t * HH + hc] = hn;
          store2_sc(Acur + (size_t)m * ASTR + hc, (unsigned)f2h(hn));
        }
      }
    }

    // drain h-stores to MALL, then publish
    asm volatile("s_waitcnt vmcnt(0)" ::: "memory");
    __builtin_amdgcn_s_barrier();
    if (tid == 0) store4_sc(&flags[Mt * 64 + Nt], (unsigned)(t + 1));
  }
}

extern "C" void kernel_launch(void* const* d_in, const int* in_sizes, int n_in,
                              void* d_out, int out_size, void* d_ws, size_t ws_size,
                              hipStream_t stream) {
  const float* X    = (const float*)d_in[0];
  const float* lami = (const float*)d_in[1];
  const float* bvi  = (const float*)d_in[2];
  const float* Wi   = (const float*)d_in[3];
  const float* bi   = (const float*)d_in[4];
  const float* lamf = (const float*)d_in[5];
  const float* bvf  = (const float*)d_in[6];
  const float* Wf   = (const float*)d_in[7];
  const float* bf_  = (const float*)d_in[8];
  const float* lamg = (const float*)d_in[9];
  const float* bvg  = (const float*)d_in[10];
  const float* Wg   = (const float*)d_in[11];
  const float* bg   = (const float*)d_in[12];
  const float* lamo = (const float*)d_in[13];
  const float* bvo  = (const float*)d_in[14];
  const float* Wo   = (const float*)d_in[15];
  const float* bo   = (const float*)d_in[16];

  float* out = (float*)d_out;

  // workspace layout (~8.8 MB)
  float* sT    = (float*)d_ws;                          // 512*128 f32
  float* lamP  = sT + (size_t)NN * LL;                  // 4096 f32
  float* biasP = lamP + NJ;                             // 4096 f32
  unsigned short* Ag0 = (unsigned short*)(biasP + NJ);  // 128*1024 fp16
  unsigned short* Ag1 = Ag0 + (size_t)NN * ASTR;        // 128*1024 fp16
  unsigned short* Bb  = Ag1 + (size_t)NN * ASTR;        // 4096*1024 fp16 (8 MB)
  unsigned* flags = (unsigned*)(Bb + (size_t)NJ * BSTR);// 256 u32

  zero_flags_kernel<<<1, 256, 0, stream>>>(flags);
  sum_rows_kernel<<<(NN * LL) / 4, 256, 0, stream>>>(X, sT);
  wpack_kernel<<<(NJ * 128) / 256, 256, 0, stream>>>(Wi, Wf, Wg, Wo, Bb);
  pack_kernel<<<NJ / 256, 256, 0, stream>>>(lami, lamf, lamg, lamo,
                                            bvi, bvf, bvg, bvo,
                                            bi, bf_, bg, bo, lamP, biasP);

  persist_kernel<<<dim3(256), dim3(256), 0, stream>>>(Bb, sT, lamP, biasP,
                                                      out, Ag0, Ag1, flags);
}

// Round 16
// 3747.538 us; speedup vs baseline: 1.1959x; 1.1352x over previous
//
#include <hip/hip_runtime.h>
#include <cstdint>
#include <cstddef>

#define NN 128
#define LL 512
#define DD 512
#define HH 1024
#define NJ 4096            // packed gate cols, j = 4*hc + g
#define ASTR 1024          // A row stride (fp16 elems)
#define BSTR 1024          // B row stride (fp16 elems)
#define NCH 4              // K chunks of 256 (each = 2 sub-chunks of 128)

typedef __attribute__((ext_vector_type(8))) _Float16 half8;
typedef __attribute__((ext_vector_type(4))) float f32x4;

__device__ __forceinline__ unsigned short f2h(float x) {
  union { _Float16 h; unsigned short u; } v; v.h = (_Float16)x; return v.u;
}
__device__ __forceinline__ float sigf(float x) { return 1.0f / (1.0f + __expf(-x)); }

__device__ __forceinline__ void glds16(const void* g, const void* l) {
  __builtin_amdgcn_global_load_lds(
      (const __attribute__((address_space(1))) unsigned int*)g,
      (__attribute__((address_space(3))) unsigned int*)l, 16, 0, 0);
}

// ---------------- sT[l*NN + n] = sum_d X[n,l,d] ----------------
__global__ __launch_bounds__(256)
void sum_rows_kernel(const float* __restrict__ X, float* __restrict__ sT) {
  int row  = blockIdx.x * 4 + (threadIdx.x >> 6);
  int lane = threadIdx.x & 63;
  const float* x = X + (size_t)row * DD + lane * 8;
  float4 a = *(const float4*)x;
  float4 b = *(const float4*)(x + 4);
  float v = (a.x + a.y) + (a.z + a.w) + (b.x + b.y) + (b.z + b.w);
#pragma unroll
  for (int off = 32; off > 0; off >>= 1) v += __shfl_down(v, off, 64);
  if (lane == 0) {
    int n = row >> 9, l = row & 511;
    sT[l * NN + n] = v;
  }
}

// ---------------- pack W into fp16, gate-interleaved rows ----------------
__global__ __launch_bounds__(256)
void wpack_kernel(const float* __restrict__ Wi, const float* __restrict__ Wf,
                  const float* __restrict__ Wg, const float* __restrict__ Wo,
                  unsigned short* __restrict__ B) {
  int idx = blockIdx.x * 256 + threadIdx.x;    // NJ*128 threads
  int j = idx >> 7;
  int k = (idx & 127) << 3;
  int hc = j >> 2, g = j & 3;
  const float* W = (g == 0) ? Wi : (g == 1) ? Wf : (g == 2) ? Wg : Wo;
  const float4 x0 = *(const float4*)(W + (size_t)hc * HH + k);
  const float4 x1 = *(const float4*)(W + (size_t)hc * HH + k + 4);
  float xv[8] = {x0.x, x0.y, x0.z, x0.w, x1.x, x1.y, x1.z, x1.w};
  unsigned short* d = B + (size_t)j * BSTR + k;
#pragma unroll
  for (int e = 0; e < 8; ++e) d[e] = f2h(xv[e]);
}

// ---------------- pack lambda / (binv+b) gate-interleaved ----------------
__global__ __launch_bounds__(256)
void pack_kernel(const float* li, const float* lf, const float* lg, const float* lo_,
                 const float* bvi, const float* bvf, const float* bvg, const float* bvo,
                 const float* bi, const float* bf_, const float* bg, const float* bo,
                 float* __restrict__ lamP, float* __restrict__ biasP) {
  int j = blockIdx.x * 256 + threadIdx.x;
  int hc = j >> 2, g = j & 3;
  const float* lam = (g == 0) ? li : (g == 1) ? lf : (g == 2) ? lg : lo_;
  const float* bv  = (g == 0) ? bvi : (g == 1) ? bvf : (g == 2) ? bvg : bvo;
  const float* bb  = (g == 0) ? bi : (g == 1) ? bf_ : (g == 2) ? bg : bo;
  lamP[j] = lam[hc];
  biasP[j] = bv[hc] + bb[hc];
}

// ---------------- t = 0 (h=0, c=0: no GEMM) ----------------
__global__ __launch_bounds__(256)
void t0_kernel(const float* __restrict__ sT, const float* __restrict__ lamP,
               const float* __restrict__ biasP, float* __restrict__ out,
               float* __restrict__ cbuf, unsigned short* __restrict__ A0) {
  int id = blockIdx.x * 256 + threadIdx.x;   // NN*HH threads
  int n = id >> 10, hc = id & 1023;
  float sv = sT[n];                          // t = 0 slice
  float4 lam = *(const float4*)(lamP + 4 * hc);
  float4 bia = *(const float4*)(biasP + 4 * hc);
  float vi = sigf(sv * lam.x + bia.x);
  float vg = sigf(sv * lam.z + bia.z);
  float vo = sigf(sv * lam.w + bia.w);
  float cn = vi * vg;
  float hn = vo * sigf(cn);
  cbuf[n * HH + hc] = cn;
  out[(size_t)n * (LL * HH) + hc] = hn;
  A0[(size_t)n * ASTR + hc] = f2h(hn);
}

// ---------------- one LSTM step: fp16 GEMM, 2 independent blocks per CU ----------------
// grid 512 (XCD-swizzled, 2 blocks/CU), block 128 thr = 2 waves (j-split 2x16).
// block tile 32m x 32j x K1024; wave tile 32m x 16j — R11's exact fragment math.
// LDS: A [2sub][32][128] + B [2sub][32][128] fp16 = 32 KB x 2 buffers = 64 KB
// -> 2 blocks/CU co-resident: two INDEPENDENT barrier domains overlap each
// other's stage/vmcnt/barrier stalls (the m97/m114 mechanism R11 lacked).
// Staging: 32 x 1KB pieces/chunk, 16/wave, counted vmcnt(16). Same swizzle.
__global__ __launch_bounds__(128, 2)
void step_kernel(const unsigned short* __restrict__ Aprev,
                 const unsigned short* __restrict__ Bbuf,
                 const float* __restrict__ sT, const float* __restrict__ lamP,
                 const float* __restrict__ biasP, float* __restrict__ out,
                 float* __restrict__ cbuf, unsigned short* __restrict__ Acur, int t)
{
  __shared__ alignas(16) short lds[2][16384];   // 32 KB x 2

  const int tid = threadIdx.x;
  const int ln  = tid & 63;
  const int w   = tid >> 6;          // wave 0..1

  // XCD-contiguous mapping: XCD x owns wl in [64x, 64x+64)
  const int bid = blockIdx.x;
  const int wl  = (bid & 7) * 64 + (bid >> 3);
  const int Nt  = wl >> 2;           // 0..127 (j tile, 32 wide)
  const int Mt  = wl & 3;            // 0..3   (m tile)
  const int n0  = Mt * 32;
  const int j0  = Nt * 32;

  // --- staging piece table: 32 pieces of 1KB/chunk; wave w owns 16 ---
  const char* srcb[16];
  int ldsoff[16];
  {
    const int ps = ln & 15;
    const int rr = ln >> 4;
#pragma unroll
    for (int i = 0; i < 16; ++i) {
      int p = w * 16 + i;            // 0..31
      const char* s; int off;
      if (p < 16) {                  // A: 16 pieces (2 subs x 8)
        int sub = p >> 3, pr = p & 7;
        int r = pr * 4 + rr;         // 0..31
        int sp = (ps & 8) | ((ps ^ r) & 7);
        s = (const char*)(Aprev + (size_t)(n0 + r) * ASTR + sub * 128 + sp * 8);
        off = sub * 4096 + pr * 512;
      } else {                       // B: 16 pieces (2 subs x 8)
        int q = p - 16;
        int sub = q >> 3, pr = q & 7;
        int r = pr * 4 + rr;         // 0..31
        int sp = (ps & 8) | ((ps ^ r) & 7);
        s = (const char*)(Bbuf + (size_t)(j0 + r) * BSTR + sub * 128 + sp * 8);
        off = 8192 + sub * 4096 + pr * 512;
      }
      srcb[i] = s; ldsoff[i] = off;
    }
  }

  // --- fragment read offsets (proven 128-col swizzle per sub-plane) ---
  int aoff[2][8], boff[8];
  {
    const int hs = ln >> 4;
#pragma unroll
    for (int sl = 0; sl < 8; ++sl) {
      int sub = sl >> 2;
      int s   = (sl & 3) * 4 + hs;
#pragma unroll
      for (int mf = 0; mf < 2; ++mf) {
        int rA = mf * 16 + (ln & 15);
        aoff[mf][sl] = sub * 4096 + rA * 128 + (((s & 8) | ((s ^ rA) & 7)) << 3);
      }
      int rB = w * 16 + (ln & 15);   // 0..31 within block's B plane
      boff[sl] = 8192 + sub * 4096 + rB * 128 + (((s & 8) | ((s ^ rB) & 7)) << 3);
    }
  }

  // --- epilogue constants + prefetch (hide L2 latency under the K-loop) ---
  const int jj = j0 + w * 16 + (ln & 15);
  const float lamv = lamP[jj];
  const float biav = biasP[jj];
  const int rbase = (ln >> 4) * 4;
  const int hc = jj >> 2;
  float cold[2][4], svp[2][4];
#pragma unroll
  for (int mf = 0; mf < 2; ++mf)
#pragma unroll
    for (int r = 0; r < 4; ++r) {
      const int m = n0 + mf * 16 + rbase + r;
      cold[mf][r] = cbuf[m * HH + hc];
      svp[mf][r]  = sT[t * NN + m];
    }
  __builtin_amdgcn_sched_barrier(0);

  f32x4 acc0 = {0.f,0.f,0.f,0.f};
  f32x4 acc1 = {0.f,0.f,0.f,0.f};

  auto stage = [&](int c, int b) {
    const int co = c * 512;            // K256 chunk = 512 B per row
#pragma unroll
    for (int i = 0; i < 16; ++i) glds16(srcb[i] + co, &lds[b][ldsoff[i]]);
  };

  stage(0, 0);
  __builtin_amdgcn_sched_barrier(0);
#pragma unroll
  for (int c = 0; c < NCH; ++c) {
    const int b = c & 1;
    __builtin_amdgcn_s_barrier();               // prev compute done: buf b^1 free
    if (c < NCH - 1) {
      stage(c + 1, b ^ 1);
      __builtin_amdgcn_sched_barrier(0);
      asm volatile("s_waitcnt vmcnt(16)" ::: "memory");  // chunk c landed; c+1 in flight
    } else {
      asm volatile("s_waitcnt vmcnt(0)" ::: "memory");
    }
    __builtin_amdgcn_s_barrier();               // all waves see chunk c
#pragma unroll
    for (int sl = 0; sl < 8; ++sl) {
      half8 a0 = *(const half8*)&lds[b][aoff[0][sl]];
      half8 a1 = *(const half8*)&lds[b][aoff[1][sl]];
      half8 bb = *(const half8*)&lds[b][boff[sl]];
      acc0 = __builtin_amdgcn_mfma_f32_16x16x32_f16(a0, bb, acc0, 0, 0, 0);
      acc1 = __builtin_amdgcn_mfma_f32_16x16x32_f16(a1, bb, acc1, 0, 0, 0);
    }
  }

  // ---- epilogue: fuse 4 gates (adjacent lanes) -> c,h ; emit h + h_fp16 ----
#pragma unroll
  for (int mf = 0; mf < 2; ++mf) {
    const int m0 = n0 + mf * 16 + rbase;
#pragma unroll
    for (int r = 0; r < 4; ++r) {
      const int m = m0 + r;
      float a = (mf == 0) ? acc0[r] : acc1[r];
      float v = sigf(a + svp[mf][r] * lamv + biav);
      const int base = ln & ~3;
      float vi = __shfl(v, base + 0, 64);
      float vf = __shfl(v, base + 1, 64);
      float vg = __shfl(v, base + 2, 64);
      float vo = __shfl(v, base + 3, 64);
      if ((ln & 3) == 0) {
        float cn = vf * cold[mf][r] + vi * vg;
        float hn = vo * sigf(cn);
        cbuf[m * HH + hc] = cn;
        out[(size_t)m * (LL * HH) + (size_t)t * HH + hc] = hn;
        Acur[(size_t)m * ASTR + hc] = f2h(hn);
      }
    }
  }
}

extern "C" void kernel_launch(void* const* d_in, const int* in_sizes, int n_in,
                              void* d_out, int out_size, void* d_ws, size_t ws_size,
                              hipStream_t stream) {
  const float* X    = (const float*)d_in[0];
  const float* lami = (const float*)d_in[1];
  const float* bvi  = (const float*)d_in[2];
  const float* Wi   = (const float*)d_in[3];
  const float* bi   = (const float*)d_in[4];
  const float* lamf = (const float*)d_in[5];
  const float* bvf  = (const float*)d_in[6];
  const float* Wf   = (const float*)d_in[7];
  const float* bf_  = (const float*)d_in[8];
  const float* lamg = (const float*)d_in[9];
  const float* bvg  = (const float*)d_in[10];
  const float* Wg   = (const float*)d_in[11];
  const float* bg   = (const float*)d_in[12];
  const float* lamo = (const float*)d_in[13];
  const float* bvo  = (const float*)d_in[14];
  const float* Wo   = (const float*)d_in[15];
  const float* bo   = (const float*)d_in[16];

  float* out  = (float*)d_out;

  // workspace layout (~9.7 MB)
  float* cbuf  = (float*)d_ws;                         // 128*1024 f32
  float* sT    = cbuf + (size_t)NN * HH;               // 512*128  f32
  float* lamP  = sT + (size_t)NN * LL;                 // 4096 f32
  float* biasP = lamP + NJ;                            // 4096 f32
  unsigned short* A0 = (unsigned short*)(biasP + NJ);  // 128*1024 fp16
  unsigned short* A1 = A0 + (size_t)NN * ASTR;         // 128*1024 fp16
  unsigned short* Bb = A1 + (size_t)NN * ASTR;         // 4096*1024 fp16 (8 MB)

  sum_rows_kernel<<<(NN * LL) / 4, 256, 0, stream>>>(X, sT);
  wpack_kernel<<<(NJ * 128) / 256, 256, 0, stream>>>(Wi, Wf, Wg, Wo, Bb);
  pack_kernel<<<NJ / 256, 256, 0, stream>>>(lami, lamf, lamg, lamo,
                                            bvi, bvf, bvg, bvo,
                                            bi, bf_, bg, bo, lamP, biasP);
  t0_kernel<<<(NN * HH) / 256, 256, 0, stream>>>(sT, lamP, biasP, out, cbuf, A0);

  for (int t = 1; t < LL; ++t) {
    const unsigned short* Ap = (t & 1) ? A0 : A1;
    unsigned short* Ac = (t & 1) ? (unsigned short*)A1 : A0;
    step_kernel<<<512, 128, 0, stream>>>(Ap, Bb, sT, lamP, biasP, out, cbuf, Ac, t);
  }
}